// Round 6
// baseline (574.489 us; speedup 1.0000x reference)
//
#include <hip/hip_runtime.h>
#include <math.h>

#define NV 3
#define DIMX 128
#define HD 64
#define NVH 192
#define NBLK 256     // edge-partition blocks for hist/scatter
#define NBUK 128     // dst buckets of 512 nodes
#define BSH 9        // log2(512)

typedef unsigned int uint32;
typedef unsigned short ushort16;
typedef unsigned char uchar;
typedef __attribute__((ext_vector_type(8))) short short8;
typedef __attribute__((ext_vector_type(4))) float f32x4;

__device__ __forceinline__ unsigned fkey(float f){
  unsigned b = __float_as_uint(f);
  return (b & 0x80000000u) ? ~b : (b | 0x80000000u);
}
__device__ __forceinline__ float unkey(unsigned k){
  return __uint_as_float((k & 0x80000000u) ? (k ^ 0x80000000u) : ~k);
}
__device__ __forceinline__ uint32 bf16rne(float f){
  uint32 u = __float_as_uint(f);
  return (u + 0x7fffu + ((u >> 16) & 1u)) >> 16;
}
__device__ __forceinline__ float bfus(uint32 q){ return __uint_as_float(q << 16); }

// ---- CSR build: two-level counting sort, LDS atomics only ----
__global__ __launch_bounds__(256) void k_hist(const int* __restrict__ ei, int E, int EPB,
                                              int* __restrict__ histT){
  __shared__ int sh[NBUK];
  int t = threadIdx.x, b = blockIdx.x;
  if (t < NBUK) sh[t] = 0;
  __syncthreads();
  int e0 = b*EPB, e1 = min(e0 + EPB, E);
  for (int i = e0 + t; i < e1; i += 256){
    int d = ei[E + i];
    atomicAdd(&sh[d >> BSH], 1);
  }
  __syncthreads();
  if (t < NBUK) histT[t*NBLK + b] = sh[t];
}

__global__ __launch_bounds__(1024) void k_hscan(int* __restrict__ histT){
  __shared__ int sh[1024];
  int t = threadIdx.x;
  int lo = t*32;
  int vals[32]; int s = 0;
  #pragma unroll
  for (int k = 0; k < 32; ++k){ vals[k] = histT[lo+k]; s += vals[k]; }
  sh[t] = s; __syncthreads();
  for (int ofs = 1; ofs < 1024; ofs <<= 1){
    int v = (t >= ofs) ? sh[t-ofs] : 0;
    __syncthreads();
    sh[t] += v;
    __syncthreads();
  }
  int run = sh[t] - s;
  #pragma unroll
  for (int k = 0; k < 32; ++k){ histT[lo+k] = run; run += vals[k]; }
}

// pack edge as (dst_local<<16)|src  (valid: src < 65536, dst_local < 512)
__global__ __launch_bounds__(256) void k_scatter(const int* __restrict__ ei, int E, int EPB,
                                                 const int* __restrict__ ofsT, uint32* __restrict__ ebuf){
  __shared__ int cur[NBUK];
  int t = threadIdx.x, b = blockIdx.x;
  if (t < NBUK) cur[t] = ofsT[t*NBLK + b];
  __syncthreads();
  int e0 = b*EPB, e1 = min(e0 + EPB, E);
  for (int i = e0 + t; i < e1; i += 256){
    int s = ei[i], d = ei[E + i];
    int pos = atomicAdd(&cur[d >> BSH], 1);
    ebuf[pos] = ((uint32)(d & 511) << 16) | (uint32)s;
  }
}

__global__ __launch_bounds__(512) void k_csr(const uint32* __restrict__ ebuf, const int* __restrict__ ofsT,
                                             int E, int N, int* __restrict__ rowstart,
                                             float* __restrict__ dinv, int* __restrict__ csr){
  __shared__ int cnt[512];
  __shared__ int pre[512];
  int t = threadIdx.x, b = blockIdx.x;
  int estart = ofsT[b*NBLK];
  int eend   = ((b+1)*NBLK < NBUK*NBLK) ? ofsT[(b+1)*NBLK] : E;
  int n0 = b << BSH;
  int nn = min(512, N - n0);
  cnt[t] = 0;
  __syncthreads();
  for (int i = estart + t; i < eend; i += 512){
    atomicAdd(&cnt[ebuf[i] >> 16], 1);
  }
  __syncthreads();
  int c = cnt[t];
  pre[t] = c;
  __syncthreads();
  for (int ofs = 1; ofs < 512; ofs <<= 1){
    int v = (t >= ofs) ? pre[t-ofs] : 0;
    __syncthreads();
    pre[t] += v;
    __syncthreads();
  }
  int excl = pre[t] - c;
  if (t < nn){
    rowstart[n0 + t] = estart + excl;
    dinv[n0 + t] = rsqrtf((float)(c + 1));
  }
  if (b == gridDim.x - 1 && t == 0) rowstart[N] = E;
  cnt[t] = estart + excl;
  __syncthreads();
  for (int i = estart + t; i < eend; i += 512){
    uint32 e = ebuf[i];
    int pos = atomicAdd(&cnt[e >> 16], 1);
    csr[pos] = (int)(e & 0xFFFFu);
  }
}

// ---- pack Wv into per-lane MFMA B-fragment order ----
__global__ __launch_bounds__(256) void k_wpack(const float* __restrict__ Wv, uint32* __restrict__ Wb){
  int t = blockIdx.x*blockDim.x + threadIdx.x;
  if (t >= 3072) return;
  int l = t & 63, s = (t >> 6) & 3, c = (t >> 8) & 3, v = t >> 10;
  int h = c*16 + (l & 15);
  int kbase = s*32 + (l >> 4)*8;
  const float* wp = Wv + v*8192 + h;
  uint32 o[4];
  #pragma unroll
  for (int jj = 0; jj < 4; ++jj){
    uint32 lo = bf16rne(wp[(kbase + 2*jj    )*64]);
    uint32 hi = bf16rne(wp[(kbase + 2*jj + 1)*64]);
    o[jj] = lo | (hi << 16);
  }
  Wb[t*4+0] = o[0]; Wb[t*4+1] = o[1]; Wb[t*4+2] = o[2]; Wb[t*4+3] = o[3];
}

// ---- MFMA linear transform fused with per-node int8 quantization ----
// byte layout per (node,view): byte jrow*4+c holds h-dim c*16+jrow  (hp(l) = (l&3)*16 + (l>>2))
__global__ __launch_bounds__(256) void k_h(const float* __restrict__ x, const uint32* __restrict__ Wb,
                                           const float* __restrict__ dinv,
                                           uint32* __restrict__ h80, uint32* __restrict__ h81,
                                           uint32* __restrict__ h82, float* __restrict__ scale, int N){
  int wave = (blockIdx.x*blockDim.x + threadIdx.x) >> 6;
  int lane = threadIdx.x & 63;
  int base = wave * 32;
  if (base >= N) return;
  int jrow = lane & 15;
  int kq   = lane >> 4;

  int nl0 = base + jrow;        if (nl0 > N-1) nl0 = N-1;
  int nl1 = base + 16 + jrow;   if (nl1 > N-1) nl1 = N-1;
  const float* xr0 = x + (size_t)nl0*384 + kq*8;
  const float* xr1 = x + (size_t)nl1*384 + kq*8;
  const short8* WB = (const short8*)Wb;

  f32x4 acc0[2][4] = {};
  f32x4 acc1[2][4] = {};
  f32x4 acc2[2][4] = {};

  #pragma unroll
  for (int v = 0; v < NV; ++v){
    #pragma unroll
    for (int s = 0; s < 4; ++s){
      const float* p0 = xr0 + v*128 + s*32;
      const float* p1 = xr1 + v*128 + s*32;
      float4 f0 = *(const float4*)p0, g0 = *(const float4*)(p0+4);
      float4 f1 = *(const float4*)p1, g1 = *(const float4*)(p1+4);
      short8 a0, a1;
      a0[0]=(short)bf16rne(f0.x); a0[1]=(short)bf16rne(f0.y); a0[2]=(short)bf16rne(f0.z); a0[3]=(short)bf16rne(f0.w);
      a0[4]=(short)bf16rne(g0.x); a0[5]=(short)bf16rne(g0.y); a0[6]=(short)bf16rne(g0.z); a0[7]=(short)bf16rne(g0.w);
      a1[0]=(short)bf16rne(f1.x); a1[1]=(short)bf16rne(f1.y); a1[2]=(short)bf16rne(f1.z); a1[3]=(short)bf16rne(f1.w);
      a1[4]=(short)bf16rne(g1.x); a1[5]=(short)bf16rne(g1.y); a1[6]=(short)bf16rne(g1.z); a1[7]=(short)bf16rne(g1.w);
      #pragma unroll
      for (int c = 0; c < 4; ++c){
        short8 b = WB[(v*4 + c)*4*64 + s*64 + lane];
        if (v == 0){
          acc0[0][c] = __builtin_amdgcn_mfma_f32_16x16x32_bf16(a0, b, acc0[0][c], 0, 0, 0);
          acc0[1][c] = __builtin_amdgcn_mfma_f32_16x16x32_bf16(a1, b, acc0[1][c], 0, 0, 0);
        } else if (v == 1){
          acc1[0][c] = __builtin_amdgcn_mfma_f32_16x16x32_bf16(a0, b, acc1[0][c], 0, 0, 0);
          acc1[1][c] = __builtin_amdgcn_mfma_f32_16x16x32_bf16(a1, b, acc1[1][c], 0, 0, 0);
        } else {
          acc2[0][c] = __builtin_amdgcn_mfma_f32_16x16x32_bf16(a0, b, acc2[0][c], 0, 0, 0);
          acc2[1][c] = __builtin_amdgcn_mfma_f32_16x16x32_bf16(a1, b, acc2[1][c], 0, 0, 0);
        }
      }
    }
  }

  #pragma unroll
  for (int rt = 0; rt < 2; ++rt){
    #pragma unroll
    for (int r = 0; r < 4; ++r){
      int n = base + rt*16 + kq*4 + r;          // same for all 16 lanes of this kq group
      float dv = (n < N) ? dinv[n] : 0.f;
      float v0[4], v1[4], v2[4];
      float m = 0.f;
      #pragma unroll
      for (int c = 0; c < 4; ++c){
        v0[c] = acc0[rt][c][r]*dv;
        v1[c] = acc1[rt][c][r]*dv;
        v2[c] = acc2[rt][c][r]*dv;
        m = fmaxf(m, fabsf(v0[c]));
        m = fmaxf(m, fabsf(v1[c]));
        m = fmaxf(m, fabsf(v2[c]));
      }
      #pragma unroll
      for (int ofs = 1; ofs < 16; ofs <<= 1) m = fmaxf(m, __shfl_xor(m, ofs));
      float inv = (m > 0.f) ? 127.0f/m : 0.f;
      uint32 p0 = 0, p1 = 0, p2 = 0;
      #pragma unroll
      for (int c = 0; c < 4; ++c){
        uint32 q0 = (uint32)(int)(v0[c]*inv + 128.5f);
        uint32 q1 = (uint32)(int)(v1[c]*inv + 128.5f);
        uint32 q2 = (uint32)(int)(v2[c]*inv + 128.5f);
        p0 |= q0 << (8*c); p1 |= q1 << (8*c); p2 |= q2 << (8*c);
      }
      if (n < N){
        h80[n*16 + jrow] = p0;
        h81[n*16 + jrow] = p1;
        h82[n*16 + jrow] = p2;
        if (jrow == 0) scale[n] = m * (1.0f/127.0f);
      }
    }
  }
}

// ---- per-view aggregation: int8 gather (3.2MB table, L2-resident) + relu + score + block max ----
__global__ __launch_bounds__(256) void k_aggv(const uchar* __restrict__ h8, const float* __restrict__ scale,
                                              const int* __restrict__ rowstart, const int* __restrict__ csr,
                                              const float* __restrict__ dinv, const float* __restrict__ bv_v,
                                              const float* __restrict__ na_w, const float* __restrict__ na_b,
                                              ushort16* __restrict__ emb_v, float* __restrict__ scores_v,
                                              unsigned* __restrict__ maxkey_v, int N){
  __shared__ unsigned bmax;
  int t = threadIdx.x;
  if (t == 0) bmax = 0u;
  __syncthreads();
  int n = blockIdx.x*4 + (t >> 6);
  int l = t & 63;
  int hp = (l & 3)*16 + (l >> 2);
  if (n < N){
    uint32 qs = h8[(size_t)n*64 + l];
    float scs = scale[n];
    float a = scs * (float)qs;
    float ssum = scs;
    int r0 = rowstart[n], r1 = rowstart[n+1];
    int i = r0;
    for (; i + 3 < r1; i += 4){
      int s0 = __builtin_nontemporal_load(&csr[i]);
      int s1 = __builtin_nontemporal_load(&csr[i+1]);
      int s2 = __builtin_nontemporal_load(&csr[i+2]);
      int s3 = __builtin_nontemporal_load(&csr[i+3]);
      uint32 q0 = h8[(size_t)s0*64 + l];
      uint32 q1 = h8[(size_t)s1*64 + l];
      uint32 q2 = h8[(size_t)s2*64 + l];
      uint32 q3 = h8[(size_t)s3*64 + l];
      float c0 = scale[s0], c1 = scale[s1], c2 = scale[s2], c3 = scale[s3];
      a = fmaf(c0, (float)q0, a);
      a = fmaf(c1, (float)q1, a);
      a = fmaf(c2, (float)q2, a);
      a = fmaf(c3, (float)q3, a);
      ssum += c0 + c1 + c2 + c3;
    }
    for (; i < r1; ++i){
      int s = __builtin_nontemporal_load(&csr[i]);
      uint32 q = h8[(size_t)s*64 + l];
      float sc = scale[s];
      a = fmaf(sc, (float)q, a);
      ssum += sc;
    }
    a -= 128.0f*ssum;
    float e = fmaxf(a*dinv[n] + bv_v[hp], 0.f);
    __builtin_nontemporal_store((ushort16)bf16rne(e), &emb_v[(size_t)n*NVH + hp]);
    float s = e * na_w[hp];
    #pragma unroll
    for (int ofs = 32; ofs >= 1; ofs >>= 1) s += __shfl_xor(s, ofs);
    if (l == 0){
      float score = s + na_b[0];
      scores_v[n] = score;
      atomicMax(&bmax, fkey(score));
    }
  }
  __syncthreads();
  if (t == 0) atomicMax(maxkey_v, bmax);
}

// ---- sum(exp) per view + weighted sum over nodes, hierarchical ----
__global__ __launch_bounds__(256) void k_wsum(const ushort16* __restrict__ emb, const float* __restrict__ scores,
                                              const unsigned* __restrict__ maxkey, float* __restrict__ wsum,
                                              float* __restrict__ sumexp, int N){
  __shared__ float shw[4][NVH];
  __shared__ float shse[4][4];
  int t = threadIdx.x;
  int lane = t & 63;
  int wv = t >> 6;
  int gw = (blockIdx.x*blockDim.x + t) >> 6;
  int nw = (gridDim.x*blockDim.x) >> 6;
  float m0 = unkey(maxkey[0]), m1 = unkey(maxkey[1]), m2 = unkey(maxkey[2]);
  float w0=0.f, w1=0.f, w2=0.f, se0=0.f, se1=0.f, se2=0.f;
  for (int n = gw; n < N; n += nw){
    const ushort16* ep = emb + (size_t)n*NVH;
    float x0 = expf(scores[n]       - m0);
    float x1 = expf(scores[N + n]   - m1);
    float x2 = expf(scores[2*N + n] - m2);
    w0 += bfus(ep[lane])*x0; w1 += bfus(ep[64+lane])*x1; w2 += bfus(ep[128+lane])*x2;
    se0 += x0; se1 += x1; se2 += x2;
  }
  shw[wv][lane]     = w0;
  shw[wv][64+lane]  = w1;
  shw[wv][128+lane] = w2;
  #pragma unroll
  for (int ofs = 32; ofs >= 1; ofs >>= 1){
    se0 += __shfl_xor(se0, ofs);
    se1 += __shfl_xor(se1, ofs);
    se2 += __shfl_xor(se2, ofs);
  }
  if (lane == 0){ shse[wv][0] = se0; shse[wv][1] = se1; shse[wv][2] = se2; }
  __syncthreads();
  if (t < NVH){
    float s = shw[0][t] + shw[1][t] + shw[2][t] + shw[3][t];
    atomicAdd(&wsum[t], s);
  } else if (t >= NVH && t < NVH+3){
    int v = t - NVH;
    float s = shse[0][v] + shse[1][v] + shse[2][v] + shse[3][v];
    atomicAdd(&sumexp[v], s);
  }
}

// ---- view attention (tiny) ----
__global__ __launch_bounds__(64) void k_view(const float* __restrict__ wsum, const float* __restrict__ sumexp,
                                             const float* __restrict__ va_w1, const float* __restrict__ va_b1,
                                             const float* __restrict__ va_w2, const float* __restrict__ va_b2,
                                             float* __restrict__ g, float* __restrict__ out_vw, int N){
  __shared__ float avg[NV][64];
  __shared__ float z1[NV][32];
  int t = threadIdx.x;
  if (t < 64){
    for (int v = 0; v < NV; ++v) avg[v][t] = wsum[v*64+t] / (sumexp[v] * (float)N);
  }
  __syncthreads();
  if (t < 32){
    for (int v = 0; v < NV; ++v){
      float a = va_b1[t];
      for (int h = 0; h < 64; ++h) a += avg[v][h]*va_w1[h*32 + t];
      z1[v][t] = tanhf(a);
    }
  }
  __syncthreads();
  if (t == 0){
    float vs[NV];
    for (int v = 0; v < NV; ++v){
      float a = va_b2[0];
      for (int j = 0; j < 32; ++j) a += z1[v][j]*va_w2[j];
      vs[v] = a;
    }
    float m = fmaxf(vs[0], fmaxf(vs[1], vs[2]));
    float e0 = expf(vs[0]-m), e1 = expf(vs[1]-m), e2 = expf(vs[2]-m);
    float inv = 1.f/(e0+e1+e2);
    float vw0 = e0*inv, vw1 = e1*inv, vw2 = e2*inv;
    out_vw[0] = vw0; out_vw[1] = vw1; out_vw[2] = vw2;
    g[0] = vw0/sumexp[0]; g[1] = vw1/sumexp[1]; g[2] = vw2/sumexp[2];
  }
}

// ---- fused output + classifier + log_softmax (wave per node) ----
__global__ __launch_bounds__(256) void k_fused(const ushort16* __restrict__ emb, const float* __restrict__ scores,
                                               const unsigned* __restrict__ maxkey, const float* __restrict__ g,
                                               const float* __restrict__ cls_w, const float* __restrict__ cls_b,
                                               float* __restrict__ out, int N){
  int wid = (blockIdx.x*blockDim.x + threadIdx.x) >> 6;
  int lane = threadIdx.x & 63;
  if (wid >= N) return;
  int n = wid;
  float m0 = unkey(maxkey[0]), m1 = unkey(maxkey[1]), m2 = unkey(maxkey[2]);
  float w0 = expf(scores[n]       - m0)*g[0];
  float w1 = expf(scores[N + n]   - m1)*g[1];
  float w2 = expf(scores[2*N + n] - m2)*g[2];
  const ushort16* ep = emb + (size_t)n*NVH;
  float fu = bfus(ep[lane])*w0 + bfus(ep[64+lane])*w1 + bfus(ep[128+lane])*w2;
  out[(size_t)2*N + (size_t)n*64 + lane] = fu;
  float c0 = fu*cls_w[lane*2 + 0];
  float c1 = fu*cls_w[lane*2 + 1];
  #pragma unroll
  for (int ofs = 32; ofs >= 1; ofs >>= 1){
    c0 += __shfl_xor(c0, ofs);
    c1 += __shfl_xor(c1, ofs);
  }
  if (lane == 0){
    float l0 = c0 + cls_b[0], l1 = c1 + cls_b[1];
    float m = fmaxf(l0, l1);
    float lse = m + logf(expf(l0-m) + expf(l1-m));
    out[(size_t)n*2]     = l0 - lse;
    out[(size_t)n*2 + 1] = l1 - lse;
  }
}

extern "C" void kernel_launch(void* const* d_in, const int* in_sizes, int n_in,
                              void* d_out, int out_size, void* d_ws, size_t ws_size,
                              hipStream_t stream){
  const float* x     = (const float*)d_in[0];
  const int*   ei    = (const int*)d_in[1];
  const float* Wv    = (const float*)d_in[2];
  const float* bv    = (const float*)d_in[3];
  const float* na_w  = (const float*)d_in[4];
  const float* na_b  = (const float*)d_in[5];
  const float* va_w1 = (const float*)d_in[6];
  const float* va_b1 = (const float*)d_in[7];
  const float* va_w2 = (const float*)d_in[8];
  const float* va_b2 = (const float*)d_in[9];
  const float* cls_w = (const float*)d_in[10];
  const float* cls_b = (const float*)d_in[11];
  int N = in_sizes[0] / (NV*DIMX);
  int E = in_sizes[1] / 2;
  float* out = (float*)d_out;

  char* wptr = (char*)d_ws;
  size_t off = 0;
  auto alloc = [&](size_t bytes){ void* p = wptr + off; off += (bytes + 255) & ~255ull; return p; };
  uint32*    h80      = (uint32*)alloc((size_t)N*64);
  uint32*    h81      = (uint32*)alloc((size_t)N*64);
  uint32*    h82      = (uint32*)alloc((size_t)N*64);
  float*     scale    = (float*)alloc((size_t)N*4);
  ushort16*  emb      = (ushort16*)alloc((size_t)N*NVH*2);
  int*       csr      = (int*)alloc((size_t)E*4);
  uint32*    ebuf     = (uint32*)alloc((size_t)E*4);
  int*       histT    = (int*)alloc((size_t)NBUK*NBLK*4);
  int*       rowstart = (int*)alloc((size_t)(N+1)*4);
  float*     dinv     = (float*)alloc((size_t)N*4);
  float*     scores   = (float*)alloc((size_t)3*N*4);
  unsigned*  maxkey   = (unsigned*)alloc(3*4);
  float*     sumexp   = (float*)alloc(3*4);
  float*     wsum     = (float*)alloc(192*4);
  float*     g        = (float*)alloc(3*4);
  uint32*    Wb       = (uint32*)alloc(3072*16);

  hipMemsetAsync(maxkey, 0, 3*4, stream);
  hipMemsetAsync(sumexp, 0, 3*4, stream);
  hipMemsetAsync(wsum,   0, 192*4, stream);

  int EPB = (E + NBLK - 1) / NBLK;
  int nbuck = (N + 511) >> BSH;
  k_hist   <<<NBLK, 256, 0, stream>>>(ei, E, EPB, histT);
  k_hscan  <<<1, 1024, 0, stream>>>(histT);
  k_scatter<<<NBLK, 256, 0, stream>>>(ei, E, EPB, histT, ebuf);
  k_csr    <<<nbuck, 512, 0, stream>>>(ebuf, histT, E, N, rowstart, dinv, csr);
  k_wpack  <<<12, 256, 0, stream>>>(Wv, Wb);
  int waves = (N + 31) / 32;
  k_h      <<<(waves*64+255)/256, 256, 0, stream>>>(x, Wb, dinv, h80, h81, h82, scale, N);
  int gagg = (N + 3) / 4;
  k_aggv   <<<gagg, 256, 0, stream>>>((const uchar*)h80, scale, rowstart, csr, dinv, bv,
                                      na_w, na_b, emb,      scores,       maxkey,   N);
  k_aggv   <<<gagg, 256, 0, stream>>>((const uchar*)h81, scale, rowstart, csr, dinv, bv + 64,
                                      na_w, na_b, emb + 64, scores + N,   maxkey+1, N);
  k_aggv   <<<gagg, 256, 0, stream>>>((const uchar*)h82, scale, rowstart, csr, dinv, bv + 128,
                                      na_w, na_b, emb + 128, scores + 2*N, maxkey+2, N);
  k_wsum   <<<304, 256, 0, stream>>>(emb, scores, maxkey, wsum, sumexp, N);
  k_view   <<<1, 64, 0, stream>>>(wsum, sumexp, va_w1, va_b1, va_w2, va_b2, g,
                                  out + (size_t)2*N + (size_t)N*64, N);
  k_fused  <<<(N*64+255)/256, 256, 0, stream>>>(emb, scores, maxkey, g, cls_w, cls_b, out, N);
}

// Round 7
// 256.304 us; speedup vs baseline: 2.2414x; 2.2414x over previous
//
#include <hip/hip_runtime.h>
#include <math.h>

#define NV 3
#define DIMX 128
#define HD 64
#define NVH 192
#define NBLK 256     // edge-partition blocks for hist/scatter
#define NBUK 128     // dst buckets of 512 nodes
#define BSH 9        // log2(512)

typedef unsigned int uint32;
typedef unsigned short ushort16;
typedef unsigned char uchar;
typedef __attribute__((ext_vector_type(8))) short short8;
typedef __attribute__((ext_vector_type(4))) float f32x4;

__device__ __forceinline__ unsigned fkey(float f){
  unsigned b = __float_as_uint(f);
  return (b & 0x80000000u) ? ~b : (b | 0x80000000u);
}
__device__ __forceinline__ float unkey(unsigned k){
  return __uint_as_float((k & 0x80000000u) ? (k ^ 0x80000000u) : ~k);
}
__device__ __forceinline__ uint32 bf16rne(float f){
  uint32 u = __float_as_uint(f);
  return (u + 0x7fffu + ((u >> 16) & 1u)) >> 16;
}
__device__ __forceinline__ float bfus(uint32 q){ return __uint_as_float(q << 16); }

// ---- CSR build: two-level counting sort, LDS atomics only ----
__global__ __launch_bounds__(256) void k_hist(const int* __restrict__ ei, int E, int EPB,
                                              int* __restrict__ histT){
  __shared__ int sh[NBUK];
  int t = threadIdx.x, b = blockIdx.x;
  if (t < NBUK) sh[t] = 0;
  __syncthreads();
  int e0 = b*EPB, e1 = min(e0 + EPB, E);
  for (int i = e0 + t; i < e1; i += 256){
    int d = ei[E + i];
    atomicAdd(&sh[d >> BSH], 1);
  }
  __syncthreads();
  if (t < NBUK) histT[t*NBLK + b] = sh[t];
}

__global__ __launch_bounds__(1024) void k_hscan(int* __restrict__ histT){
  __shared__ int sh[1024];
  int t = threadIdx.x;
  int lo = t*32;
  int vals[32]; int s = 0;
  #pragma unroll
  for (int k = 0; k < 32; ++k){ vals[k] = histT[lo+k]; s += vals[k]; }
  sh[t] = s; __syncthreads();
  for (int ofs = 1; ofs < 1024; ofs <<= 1){
    int v = (t >= ofs) ? sh[t-ofs] : 0;
    __syncthreads();
    sh[t] += v;
    __syncthreads();
  }
  int run = sh[t] - s;
  #pragma unroll
  for (int k = 0; k < 32; ++k){ histT[lo+k] = run; run += vals[k]; }
}

// pack edge as (dst_local<<16)|src  (valid: src < 65536, dst_local < 512)
__global__ __launch_bounds__(256) void k_scatter(const int* __restrict__ ei, int E, int EPB,
                                                 const int* __restrict__ ofsT, uint32* __restrict__ ebuf){
  __shared__ int cur[NBUK];
  int t = threadIdx.x, b = blockIdx.x;
  if (t < NBUK) cur[t] = ofsT[t*NBLK + b];
  __syncthreads();
  int e0 = b*EPB, e1 = min(e0 + EPB, E);
  for (int i = e0 + t; i < e1; i += 256){
    int s = ei[i], d = ei[E + i];
    int pos = atomicAdd(&cur[d >> BSH], 1);
    ebuf[pos] = ((uint32)(d & 511) << 16) | (uint32)s;
  }
}

__global__ __launch_bounds__(512) void k_csr(const uint32* __restrict__ ebuf, const int* __restrict__ ofsT,
                                             int E, int N, int* __restrict__ rowstart,
                                             float* __restrict__ dinv, int* __restrict__ csr){
  __shared__ int cnt[512];
  __shared__ int pre[512];
  int t = threadIdx.x, b = blockIdx.x;
  int estart = ofsT[b*NBLK];
  int eend   = ((b+1)*NBLK < NBUK*NBLK) ? ofsT[(b+1)*NBLK] : E;
  int n0 = b << BSH;
  int nn = min(512, N - n0);
  cnt[t] = 0;
  __syncthreads();
  for (int i = estart + t; i < eend; i += 512){
    atomicAdd(&cnt[ebuf[i] >> 16], 1);
  }
  __syncthreads();
  int c = cnt[t];
  pre[t] = c;
  __syncthreads();
  for (int ofs = 1; ofs < 512; ofs <<= 1){
    int v = (t >= ofs) ? pre[t-ofs] : 0;
    __syncthreads();
    pre[t] += v;
    __syncthreads();
  }
  int excl = pre[t] - c;
  if (t < nn){
    rowstart[n0 + t] = estart + excl;
    dinv[n0 + t] = rsqrtf((float)(c + 1));
  }
  if (b == gridDim.x - 1 && t == 0) rowstart[N] = E;
  cnt[t] = estart + excl;
  __syncthreads();
  for (int i = estart + t; i < eend; i += 512){
    uint32 e = ebuf[i];
    int pos = atomicAdd(&cnt[e >> 16], 1);
    csr[pos] = (int)(e & 0xFFFFu);
  }
}

// ---- pack Wv into per-lane MFMA B-fragment order ----
__global__ __launch_bounds__(256) void k_wpack(const float* __restrict__ Wv, uint32* __restrict__ Wb){
  int t = blockIdx.x*blockDim.x + threadIdx.x;
  if (t >= 3072) return;
  int l = t & 63, s = (t >> 6) & 3, c = (t >> 8) & 3, v = t >> 10;
  int h = c*16 + (l & 15);
  int kbase = s*32 + (l >> 4)*8;
  const float* wp = Wv + v*8192 + h;
  uint32 o[4];
  #pragma unroll
  for (int jj = 0; jj < 4; ++jj){
    uint32 lo = bf16rne(wp[(kbase + 2*jj    )*64]);
    uint32 hi = bf16rne(wp[(kbase + 2*jj + 1)*64]);
    o[jj] = lo | (hi << 16);
  }
  Wb[t*4+0] = o[0]; Wb[t*4+1] = o[1]; Wb[t*4+2] = o[2]; Wb[t*4+3] = o[3];
}

// ---- MFMA linear transform fused with per-node int8 quantization ----
// byte layout per (node,view): byte jrow*4+c holds h-dim c*16+jrow  (hp(l) = (l&3)*16 + (l>>2))
__global__ __launch_bounds__(256) void k_h(const float* __restrict__ x, const uint32* __restrict__ Wb,
                                           const float* __restrict__ dinv,
                                           uint32* __restrict__ h80, uint32* __restrict__ h81,
                                           uint32* __restrict__ h82, float* __restrict__ scale, int N){
  int wave = (blockIdx.x*blockDim.x + threadIdx.x) >> 6;
  int lane = threadIdx.x & 63;
  int base = wave * 32;
  if (base >= N) return;
  int jrow = lane & 15;
  int kq   = lane >> 4;

  int nl0 = base + jrow;        if (nl0 > N-1) nl0 = N-1;
  int nl1 = base + 16 + jrow;   if (nl1 > N-1) nl1 = N-1;
  const float* xr0 = x + (size_t)nl0*384 + kq*8;
  const float* xr1 = x + (size_t)nl1*384 + kq*8;
  const short8* WB = (const short8*)Wb;

  f32x4 acc0[2][4] = {};
  f32x4 acc1[2][4] = {};
  f32x4 acc2[2][4] = {};

  #pragma unroll
  for (int v = 0; v < NV; ++v){
    #pragma unroll
    for (int s = 0; s < 4; ++s){
      const float* p0 = xr0 + v*128 + s*32;
      const float* p1 = xr1 + v*128 + s*32;
      float4 f0 = *(const float4*)p0, g0 = *(const float4*)(p0+4);
      float4 f1 = *(const float4*)p1, g1 = *(const float4*)(p1+4);
      short8 a0, a1;
      a0[0]=(short)bf16rne(f0.x); a0[1]=(short)bf16rne(f0.y); a0[2]=(short)bf16rne(f0.z); a0[3]=(short)bf16rne(f0.w);
      a0[4]=(short)bf16rne(g0.x); a0[5]=(short)bf16rne(g0.y); a0[6]=(short)bf16rne(g0.z); a0[7]=(short)bf16rne(g0.w);
      a1[0]=(short)bf16rne(f1.x); a1[1]=(short)bf16rne(f1.y); a1[2]=(short)bf16rne(f1.z); a1[3]=(short)bf16rne(f1.w);
      a1[4]=(short)bf16rne(g1.x); a1[5]=(short)bf16rne(g1.y); a1[6]=(short)bf16rne(g1.z); a1[7]=(short)bf16rne(g1.w);
      #pragma unroll
      for (int c = 0; c < 4; ++c){
        short8 b = WB[(v*4 + c)*4*64 + s*64 + lane];
        if (v == 0){
          acc0[0][c] = __builtin_amdgcn_mfma_f32_16x16x32_bf16(a0, b, acc0[0][c], 0, 0, 0);
          acc0[1][c] = __builtin_amdgcn_mfma_f32_16x16x32_bf16(a1, b, acc0[1][c], 0, 0, 0);
        } else if (v == 1){
          acc1[0][c] = __builtin_amdgcn_mfma_f32_16x16x32_bf16(a0, b, acc1[0][c], 0, 0, 0);
          acc1[1][c] = __builtin_amdgcn_mfma_f32_16x16x32_bf16(a1, b, acc1[1][c], 0, 0, 0);
        } else {
          acc2[0][c] = __builtin_amdgcn_mfma_f32_16x16x32_bf16(a0, b, acc2[0][c], 0, 0, 0);
          acc2[1][c] = __builtin_amdgcn_mfma_f32_16x16x32_bf16(a1, b, acc2[1][c], 0, 0, 0);
        }
      }
    }
  }

  #pragma unroll
  for (int rt = 0; rt < 2; ++rt){
    #pragma unroll
    for (int r = 0; r < 4; ++r){
      int n = base + rt*16 + kq*4 + r;          // same for all 16 lanes of this kq group
      float dv = (n < N) ? dinv[n] : 0.f;
      float v0[4], v1[4], v2[4];
      float m = 0.f;
      #pragma unroll
      for (int c = 0; c < 4; ++c){
        v0[c] = acc0[rt][c][r]*dv;
        v1[c] = acc1[rt][c][r]*dv;
        v2[c] = acc2[rt][c][r]*dv;
        m = fmaxf(m, fabsf(v0[c]));
        m = fmaxf(m, fabsf(v1[c]));
        m = fmaxf(m, fabsf(v2[c]));
      }
      #pragma unroll
      for (int ofs = 1; ofs < 16; ofs <<= 1) m = fmaxf(m, __shfl_xor(m, ofs));
      float inv = (m > 0.f) ? 127.0f/m : 0.f;
      uint32 p0 = 0, p1 = 0, p2 = 0;
      #pragma unroll
      for (int c = 0; c < 4; ++c){
        uint32 q0 = (uint32)(int)(v0[c]*inv + 128.5f);
        uint32 q1 = (uint32)(int)(v1[c]*inv + 128.5f);
        uint32 q2 = (uint32)(int)(v2[c]*inv + 128.5f);
        p0 |= q0 << (8*c); p1 |= q1 << (8*c); p2 |= q2 << (8*c);
      }
      if (n < N){
        h80[n*16 + jrow] = p0;
        h81[n*16 + jrow] = p1;
        h82[n*16 + jrow] = p2;
        if (jrow == 0) scale[n] = m * (1.0f/127.0f);
      }
    }
  }
}

// ---- per-view aggregation: int8 gather (3.2MB table, L2-resident) + relu + score ----
__global__ __launch_bounds__(256) void k_aggv(const uchar* __restrict__ h8, const float* __restrict__ scale,
                                              const int* __restrict__ rowstart, const int* __restrict__ csr,
                                              const float* __restrict__ dinv, const float* __restrict__ bv_v,
                                              const float* __restrict__ na_w, const float* __restrict__ na_b,
                                              ushort16* __restrict__ emb_v, float* __restrict__ scores_v, int N){
  int t = threadIdx.x;
  int n = blockIdx.x*4 + (t >> 6);
  int l = t & 63;
  int hp = (l & 3)*16 + (l >> 2);
  if (n >= N) return;
  uint32 qs = h8[(size_t)n*64 + l];
  float scs = scale[n];
  float a = scs * (float)qs;
  float ssum = scs;
  int r0 = rowstart[n], r1 = rowstart[n+1];
  int i = r0;
  for (; i + 3 < r1; i += 4){
    int s0 = __builtin_nontemporal_load(&csr[i]);
    int s1 = __builtin_nontemporal_load(&csr[i+1]);
    int s2 = __builtin_nontemporal_load(&csr[i+2]);
    int s3 = __builtin_nontemporal_load(&csr[i+3]);
    uint32 q0 = h8[(size_t)s0*64 + l];
    uint32 q1 = h8[(size_t)s1*64 + l];
    uint32 q2 = h8[(size_t)s2*64 + l];
    uint32 q3 = h8[(size_t)s3*64 + l];
    float c0 = scale[s0], c1 = scale[s1], c2 = scale[s2], c3 = scale[s3];
    a = fmaf(c0, (float)q0, a);
    a = fmaf(c1, (float)q1, a);
    a = fmaf(c2, (float)q2, a);
    a = fmaf(c3, (float)q3, a);
    ssum += c0 + c1 + c2 + c3;
  }
  for (; i < r1; ++i){
    int s = __builtin_nontemporal_load(&csr[i]);
    uint32 q = h8[(size_t)s*64 + l];
    float sc = scale[s];
    a = fmaf(sc, (float)q, a);
    ssum += sc;
  }
  a -= 128.0f*ssum;
  float e = fmaxf(a*dinv[n] + bv_v[hp], 0.f);
  __builtin_nontemporal_store((ushort16)bf16rne(e), &emb_v[(size_t)n*NVH + hp]);
  float s = e * na_w[hp];
  #pragma unroll
  for (int ofs = 32; ofs >= 1; ofs >>= 1) s += __shfl_xor(s, ofs);
  if (l == 0) scores_v[n] = s + na_b[0];
}

// ---- global max per view (75 blocks -> 75 atomics total) ----
__global__ void k_max(const float* __restrict__ scores, int N, unsigned* __restrict__ maxkey){
  __shared__ float sh[256];
  int v = blockIdx.y;
  const float* sp = scores + (size_t)v*N;
  int base = blockIdx.x*2048 + threadIdx.x;
  float m = -3.0e38f;
  #pragma unroll
  for (int k = 0; k < 8; ++k){
    int i = base + k*256;
    if (i < N) m = fmaxf(m, sp[i]);
  }
  sh[threadIdx.x] = m; __syncthreads();
  for (int ofs = 128; ofs >= 1; ofs >>= 1){
    if (threadIdx.x < ofs) sh[threadIdx.x] = fmaxf(sh[threadIdx.x], sh[threadIdx.x+ofs]);
    __syncthreads();
  }
  if (threadIdx.x == 0) atomicMax(&maxkey[v], fkey(sh[0]));
}

// ---- sum(exp) per view + weighted sum over nodes, hierarchical ----
__global__ __launch_bounds__(256) void k_wsum(const ushort16* __restrict__ emb, const float* __restrict__ scores,
                                              const unsigned* __restrict__ maxkey, float* __restrict__ wsum,
                                              float* __restrict__ sumexp, int N){
  __shared__ float shw[4][NVH];
  __shared__ float shse[4][4];
  int t = threadIdx.x;
  int lane = t & 63;
  int wv = t >> 6;
  int gw = (blockIdx.x*blockDim.x + t) >> 6;
  int nw = (gridDim.x*blockDim.x) >> 6;
  float m0 = unkey(maxkey[0]), m1 = unkey(maxkey[1]), m2 = unkey(maxkey[2]);
  float w0=0.f, w1=0.f, w2=0.f, se0=0.f, se1=0.f, se2=0.f;
  for (int n = gw; n < N; n += nw){
    const ushort16* ep = emb + (size_t)n*NVH;
    float x0 = expf(scores[n]       - m0);
    float x1 = expf(scores[N + n]   - m1);
    float x2 = expf(scores[2*N + n] - m2);
    w0 += bfus(ep[lane])*x0; w1 += bfus(ep[64+lane])*x1; w2 += bfus(ep[128+lane])*x2;
    se0 += x0; se1 += x1; se2 += x2;
  }
  shw[wv][lane]     = w0;
  shw[wv][64+lane]  = w1;
  shw[wv][128+lane] = w2;
  #pragma unroll
  for (int ofs = 32; ofs >= 1; ofs >>= 1){
    se0 += __shfl_xor(se0, ofs);
    se1 += __shfl_xor(se1, ofs);
    se2 += __shfl_xor(se2, ofs);
  }
  if (lane == 0){ shse[wv][0] = se0; shse[wv][1] = se1; shse[wv][2] = se2; }
  __syncthreads();
  if (t < NVH){
    float s = shw[0][t] + shw[1][t] + shw[2][t] + shw[3][t];
    atomicAdd(&wsum[t], s);
  } else if (t >= NVH && t < NVH+3){
    int v = t - NVH;
    float s = shse[0][v] + shse[1][v] + shse[2][v] + shse[3][v];
    atomicAdd(&sumexp[v], s);
  }
}

// ---- view attention (tiny) ----
__global__ __launch_bounds__(64) void k_view(const float* __restrict__ wsum, const float* __restrict__ sumexp,
                                             const float* __restrict__ va_w1, const float* __restrict__ va_b1,
                                             const float* __restrict__ va_w2, const float* __restrict__ va_b2,
                                             float* __restrict__ g, float* __restrict__ out_vw, int N){
  __shared__ float avg[NV][64];
  __shared__ float z1[NV][32];
  int t = threadIdx.x;
  if (t < 64){
    for (int v = 0; v < NV; ++v) avg[v][t] = wsum[v*64+t] / (sumexp[v] * (float)N);
  }
  __syncthreads();
  if (t < 32){
    for (int v = 0; v < NV; ++v){
      float a = va_b1[t];
      for (int h = 0; h < 64; ++h) a += avg[v][h]*va_w1[h*32 + t];
      z1[v][t] = tanhf(a);
    }
  }
  __syncthreads();
  if (t == 0){
    float vs[NV];
    for (int v = 0; v < NV; ++v){
      float a = va_b2[0];
      for (int j = 0; j < 32; ++j) a += z1[v][j]*va_w2[j];
      vs[v] = a;
    }
    float m = fmaxf(vs[0], fmaxf(vs[1], vs[2]));
    float e0 = expf(vs[0]-m), e1 = expf(vs[1]-m), e2 = expf(vs[2]-m);
    float inv = 1.f/(e0+e1+e2);
    float vw0 = e0*inv, vw1 = e1*inv, vw2 = e2*inv;
    out_vw[0] = vw0; out_vw[1] = vw1; out_vw[2] = vw2;
    g[0] = vw0/sumexp[0]; g[1] = vw1/sumexp[1]; g[2] = vw2/sumexp[2];
  }
}

// ---- fused output + classifier + log_softmax (wave per node) ----
__global__ __launch_bounds__(256) void k_fused(const ushort16* __restrict__ emb, const float* __restrict__ scores,
                                               const unsigned* __restrict__ maxkey, const float* __restrict__ g,
                                               const float* __restrict__ cls_w, const float* __restrict__ cls_b,
                                               float* __restrict__ out, int N){
  int wid = (blockIdx.x*blockDim.x + threadIdx.x) >> 6;
  int lane = threadIdx.x & 63;
  if (wid >= N) return;
  int n = wid;
  float m0 = unkey(maxkey[0]), m1 = unkey(maxkey[1]), m2 = unkey(maxkey[2]);
  float w0 = expf(scores[n]       - m0)*g[0];
  float w1 = expf(scores[N + n]   - m1)*g[1];
  float w2 = expf(scores[2*N + n] - m2)*g[2];
  const ushort16* ep = emb + (size_t)n*NVH;
  float fu = bfus(ep[lane])*w0 + bfus(ep[64+lane])*w1 + bfus(ep[128+lane])*w2;
  out[(size_t)2*N + (size_t)n*64 + lane] = fu;
  float c0 = fu*cls_w[lane*2 + 0];
  float c1 = fu*cls_w[lane*2 + 1];
  #pragma unroll
  for (int ofs = 32; ofs >= 1; ofs >>= 1){
    c0 += __shfl_xor(c0, ofs);
    c1 += __shfl_xor(c1, ofs);
  }
  if (lane == 0){
    float l0 = c0 + cls_b[0], l1 = c1 + cls_b[1];
    float m = fmaxf(l0, l1);
    float lse = m + logf(expf(l0-m) + expf(l1-m));
    out[(size_t)n*2]     = l0 - lse;
    out[(size_t)n*2 + 1] = l1 - lse;
  }
}

extern "C" void kernel_launch(void* const* d_in, const int* in_sizes, int n_in,
                              void* d_out, int out_size, void* d_ws, size_t ws_size,
                              hipStream_t stream){
  const float* x     = (const float*)d_in[0];
  const int*   ei    = (const int*)d_in[1];
  const float* Wv    = (const float*)d_in[2];
  const float* bv    = (const float*)d_in[3];
  const float* na_w  = (const float*)d_in[4];
  const float* na_b  = (const float*)d_in[5];
  const float* va_w1 = (const float*)d_in[6];
  const float* va_b1 = (const float*)d_in[7];
  const float* va_w2 = (const float*)d_in[8];
  const float* va_b2 = (const float*)d_in[9];
  const float* cls_w = (const float*)d_in[10];
  const float* cls_b = (const float*)d_in[11];
  int N = in_sizes[0] / (NV*DIMX);
  int E = in_sizes[1] / 2;
  float* out = (float*)d_out;

  char* wptr = (char*)d_ws;
  size_t off = 0;
  auto alloc = [&](size_t bytes){ void* p = wptr + off; off += (bytes + 255) & ~255ull; return p; };
  uint32*    h80      = (uint32*)alloc((size_t)N*64);
  uint32*    h81      = (uint32*)alloc((size_t)N*64);
  uint32*    h82      = (uint32*)alloc((size_t)N*64);
  float*     scale    = (float*)alloc((size_t)N*4);
  ushort16*  emb      = (ushort16*)alloc((size_t)N*NVH*2);
  int*       csr      = (int*)alloc((size_t)E*4);
  uint32*    ebuf     = (uint32*)alloc((size_t)E*4);
  int*       histT    = (int*)alloc((size_t)NBUK*NBLK*4);
  int*       rowstart = (int*)alloc((size_t)(N+1)*4);
  float*     dinv     = (float*)alloc((size_t)N*4);
  float*     scores   = (float*)alloc((size_t)3*N*4);
  unsigned*  maxkey   = (unsigned*)alloc(3*4);
  float*     sumexp   = (float*)alloc(3*4);
  float*     wsum     = (float*)alloc(192*4);
  float*     g        = (float*)alloc(3*4);
  uint32*    Wb       = (uint32*)alloc(3072*16);

  hipMemsetAsync(maxkey, 0, 3*4, stream);
  hipMemsetAsync(sumexp, 0, 3*4, stream);
  hipMemsetAsync(wsum,   0, 192*4, stream);

  int EPB = (E + NBLK - 1) / NBLK;
  int nbuck = (N + 511) >> BSH;
  k_hist   <<<NBLK, 256, 0, stream>>>(ei, E, EPB, histT);
  k_hscan  <<<1, 1024, 0, stream>>>(histT);
  k_scatter<<<NBLK, 256, 0, stream>>>(ei, E, EPB, histT, ebuf);
  k_csr    <<<nbuck, 512, 0, stream>>>(ebuf, histT, E, N, rowstart, dinv, csr);
  k_wpack  <<<12, 256, 0, stream>>>(Wv, Wb);
  int waves = (N + 31) / 32;
  k_h      <<<(waves*64+255)/256, 256, 0, stream>>>(x, Wb, dinv, h80, h81, h82, scale, N);
  int gagg = (N + 3) / 4;
  k_aggv   <<<gagg, 256, 0, stream>>>((const uchar*)h80, scale, rowstart, csr, dinv, bv,
                                      na_w, na_b, emb,       scores,       N);
  k_aggv   <<<gagg, 256, 0, stream>>>((const uchar*)h81, scale, rowstart, csr, dinv, bv + 64,
                                      na_w, na_b, emb + 64,  scores + N,   N);
  k_aggv   <<<gagg, 256, 0, stream>>>((const uchar*)h82, scale, rowstart, csr, dinv, bv + 128,
                                      na_w, na_b, emb + 128, scores + 2*N, N);
  dim3 gm((N+2047)/2048, NV);
  k_max    <<<gm, 256, 0, stream>>>(scores, N, maxkey);
  k_wsum   <<<304, 256, 0, stream>>>(emb, scores, maxkey, wsum, sumexp, N);
  k_view   <<<1, 64, 0, stream>>>(wsum, sumexp, va_w1, va_b1, va_w2, va_b2, g,
                                  out + (size_t)2*N + (size_t)N*64, N);
  k_fused  <<<(N*64+255)/256, 256, 0, stream>>>(emb, scores, maxkey, g, cls_w, cls_b, out, N);
}

// Round 8
// 184.457 us; speedup vs baseline: 3.1145x; 1.3895x over previous
//
#include <hip/hip_runtime.h>
#include <math.h>

#define NV 3
#define DIMX 128
#define HD 64
#define NVH 192
#define NBLK 256     // edge-partition blocks for hist/scatter
#define NBUK 128     // dst buckets of 512 nodes
#define BSH 9        // log2(512)

typedef unsigned int uint32;
typedef unsigned short ushort16;
typedef unsigned char uchar;
typedef __attribute__((ext_vector_type(8))) short short8;
typedef __attribute__((ext_vector_type(4))) float f32x4;

__device__ __forceinline__ unsigned fkey(float f){
  unsigned b = __float_as_uint(f);
  return (b & 0x80000000u) ? ~b : (b | 0x80000000u);
}
__device__ __forceinline__ float unkey(unsigned k){
  return __uint_as_float((k & 0x80000000u) ? (k ^ 0x80000000u) : ~k);
}
__device__ __forceinline__ uint32 bf16rne(float f){
  uint32 u = __float_as_uint(f);
  return (u + 0x7fffu + ((u >> 16) & 1u)) >> 16;
}
__device__ __forceinline__ float bfus(uint32 q){ return __uint_as_float(q << 16); }

// ---- zero the tiny accumulators (replaces 3 hipMemsetAsync) ----
__global__ void k_zero(float* __restrict__ wsum, float* __restrict__ sumexp, unsigned* __restrict__ maxkey){
  int t = threadIdx.x;
  if (t < NVH) wsum[t] = 0.f;
  else if (t < NVH+3) sumexp[t-NVH] = 0.f;
  else if (t < NVH+6) maxkey[t-NVH-3] = 0u;
}

// ---- CSR build: two-level counting sort, LDS atomics only ----
__global__ __launch_bounds__(256) void k_hist(const int* __restrict__ ei, int E, int EPB,
                                              int* __restrict__ histT){
  __shared__ int sh[NBUK];
  int t = threadIdx.x, b = blockIdx.x;
  if (t < NBUK) sh[t] = 0;
  __syncthreads();
  int e0 = b*EPB, e1 = min(e0 + EPB, E);
  for (int i = e0 + t; i < e1; i += 256){
    int d = ei[E + i];
    atomicAdd(&sh[d >> BSH], 1);
  }
  __syncthreads();
  if (t < NBUK) histT[t*NBLK + b] = sh[t];
}

__global__ __launch_bounds__(1024) void k_hscan(int* __restrict__ histT){
  __shared__ int sh[1024];
  int t = threadIdx.x;
  int lo = t*32;
  int vals[32]; int s = 0;
  #pragma unroll
  for (int k = 0; k < 32; ++k){ vals[k] = histT[lo+k]; s += vals[k]; }
  sh[t] = s; __syncthreads();
  for (int ofs = 1; ofs < 1024; ofs <<= 1){
    int v = (t >= ofs) ? sh[t-ofs] : 0;
    __syncthreads();
    sh[t] += v;
    __syncthreads();
  }
  int run = sh[t] - s;
  #pragma unroll
  for (int k = 0; k < 32; ++k){ histT[lo+k] = run; run += vals[k]; }
}

// pack edge as (dst_local<<16)|src  (valid: src < 65536, dst_local < 512)
__global__ __launch_bounds__(256) void k_scatter(const int* __restrict__ ei, int E, int EPB,
                                                 const int* __restrict__ ofsT, uint32* __restrict__ ebuf){
  __shared__ int cur[NBUK];
  int t = threadIdx.x, b = blockIdx.x;
  if (t < NBUK) cur[t] = ofsT[t*NBLK + b];
  __syncthreads();
  int e0 = b*EPB, e1 = min(e0 + EPB, E);
  for (int i = e0 + t; i < e1; i += 256){
    int s = ei[i], d = ei[E + i];
    int pos = atomicAdd(&cur[d >> BSH], 1);
    ebuf[pos] = ((uint32)(d & 511) << 16) | (uint32)s;
  }
}

__global__ __launch_bounds__(512) void k_csr(const uint32* __restrict__ ebuf, const int* __restrict__ ofsT,
                                             int E, int N, int* __restrict__ rowstart,
                                             float* __restrict__ dinv, int* __restrict__ csr){
  __shared__ int cnt[512];
  __shared__ int pre[512];
  int t = threadIdx.x, b = blockIdx.x;
  int estart = ofsT[b*NBLK];
  int eend   = ((b+1)*NBLK < NBUK*NBLK) ? ofsT[(b+1)*NBLK] : E;
  int n0 = b << BSH;
  int nn = min(512, N - n0);
  cnt[t] = 0;
  __syncthreads();
  for (int i = estart + t; i < eend; i += 512){
    atomicAdd(&cnt[ebuf[i] >> 16], 1);
  }
  __syncthreads();
  int c = cnt[t];
  pre[t] = c;
  __syncthreads();
  for (int ofs = 1; ofs < 512; ofs <<= 1){
    int v = (t >= ofs) ? pre[t-ofs] : 0;
    __syncthreads();
    pre[t] += v;
    __syncthreads();
  }
  int excl = pre[t] - c;
  if (t < nn){
    rowstart[n0 + t] = estart + excl;
    dinv[n0 + t] = rsqrtf((float)(c + 1));
  }
  if (b == gridDim.x - 1 && t == 0) rowstart[N] = E;
  cnt[t] = estart + excl;
  __syncthreads();
  for (int i = estart + t; i < eend; i += 512){
    uint32 e = ebuf[i];
    int pos = atomicAdd(&cnt[e >> 16], 1);
    csr[pos] = (int)(e & 0xFFFFu);
  }
}

// ---- pack Wv into per-lane MFMA B-fragment order ----
__global__ __launch_bounds__(256) void k_wpack(const float* __restrict__ Wv, uint32* __restrict__ Wb){
  int t = blockIdx.x*blockDim.x + threadIdx.x;
  if (t >= 3072) return;
  int l = t & 63, s = (t >> 6) & 3, c = (t >> 8) & 3, v = t >> 10;
  int h = c*16 + (l & 15);
  int kbase = s*32 + (l >> 4)*8;
  const float* wp = Wv + v*8192 + h;
  uint32 o[4];
  #pragma unroll
  for (int jj = 0; jj < 4; ++jj){
    uint32 lo = bf16rne(wp[(kbase + 2*jj    )*64]);
    uint32 hi = bf16rne(wp[(kbase + 2*jj + 1)*64]);
    o[jj] = lo | (hi << 16);
  }
  Wb[t*4+0] = o[0]; Wb[t*4+1] = o[1]; Wb[t*4+2] = o[2]; Wb[t*4+3] = o[3];
}

// ---- MFMA linear transform, one wave per (16-node tile, view), fused int8 quant ----
// combined table hq32: dword index n*48 + v*16 + jrow; byte c of dword = h-dim c*16+jrow
// per-(tile,view) scale in scaleV[v*NT + tile]
__global__ __launch_bounds__(256) void k_h(const float* __restrict__ x, const uint32* __restrict__ Wb,
                                           const float* __restrict__ dinv,
                                           uint32* __restrict__ hq32, float* __restrict__ scaleV,
                                           int N, int NT){
  int wv = (blockIdx.x*blockDim.x + threadIdx.x) >> 6;
  int lane = threadIdx.x & 63;
  int tile = wv / 3;
  int v = wv - tile*3;
  if (tile >= NT) return;
  int jrow = lane & 15;
  int kq   = lane >> 4;
  int nrow = tile*16 + jrow;
  const float* xr = x + (size_t)nrow*384 + v*128 + kq*8;
  const short8* WB = (const short8*)Wb;

  f32x4 acc[4] = {};
  #pragma unroll
  for (int s = 0; s < 4; ++s){
    const float* p = xr + s*32;
    float4 f = *(const float4*)p, g = *(const float4*)(p+4);
    short8 a;
    a[0]=(short)bf16rne(f.x); a[1]=(short)bf16rne(f.y); a[2]=(short)bf16rne(f.z); a[3]=(short)bf16rne(f.w);
    a[4]=(short)bf16rne(g.x); a[5]=(short)bf16rne(g.y); a[6]=(short)bf16rne(g.z); a[7]=(short)bf16rne(g.w);
    #pragma unroll
    for (int c = 0; c < 4; ++c){
      short8 b = WB[(v*4 + c)*256 + s*64 + lane];
      acc[c] = __builtin_amdgcn_mfma_f32_16x16x32_bf16(a, b, acc[c], 0, 0, 0);
    }
  }

  float vv[4][4];
  float mx = 0.f;
  #pragma unroll
  for (int r = 0; r < 4; ++r){
    int n = tile*16 + kq*4 + r;
    float dv = dinv[n];
    #pragma unroll
    for (int c = 0; c < 4; ++c){
      float t = acc[c][r]*dv;
      vv[c][r] = t;
      mx = fmaxf(mx, fabsf(t));
    }
  }
  #pragma unroll
  for (int ofs = 1; ofs < 64; ofs <<= 1) mx = fmaxf(mx, __shfl_xor(mx, ofs));
  float inv = (mx > 0.f) ? 127.0f/mx : 0.f;
  #pragma unroll
  for (int r = 0; r < 4; ++r){
    int n = tile*16 + kq*4 + r;
    uint32 w = 0;
    #pragma unroll
    for (int c = 0; c < 4; ++c){
      uint32 q = (uint32)(int)(vv[c][r]*inv + 128.5f);
      w |= q << (8*c);
    }
    hq32[(size_t)n*48 + v*16 + jrow] = w;
  }
  if (lane == 0) scaleV[v*NT + tile] = mx * (1.0f/127.0f);
}

// ---- fused 3-view aggregation: int8 gather (192B/edge) + relu + scores ----
// lane l covers h-dim hp = (l&3)*16 + (l>>2) (byte l of each 64B view-line)
__global__ __launch_bounds__(256) void k_aggv(const uchar* __restrict__ hq, const float* __restrict__ scaleV,
                                              const int* __restrict__ rowstart, const int* __restrict__ csr,
                                              const float* __restrict__ dinv, const float* __restrict__ bv,
                                              const float* __restrict__ na_w, const float* __restrict__ na_b,
                                              ushort16* __restrict__ emb, float* __restrict__ scores,
                                              int N, int NT){
  int wid = (blockIdx.x*blockDim.x + threadIdx.x) >> 6;
  int lane = threadIdx.x & 63;
  if (wid >= N) return;
  int n = wid;
  int hp = (lane & 3)*16 + (lane >> 2);
  // self-loop
  const uchar* hb = hq + (size_t)n*192;
  float q0 = (float)hb[lane], q1 = (float)hb[64+lane], q2 = (float)hb[128+lane];
  int grp = n >> 4;
  float c0 = scaleV[grp], c1 = scaleV[NT+grp], c2 = scaleV[2*NT+grp];
  float a0 = c0*q0, a1 = c1*q1, a2 = c2*q2;
  float ss0 = c0, ss1 = c1, ss2 = c2;
  int r0 = rowstart[n], r1 = rowstart[n+1];
  for (int base = r0; base < r1; base += 64){
    int m = r1 - base; if (m > 64) m = 64;
    int sv = (lane < m) ? __builtin_nontemporal_load(&csr[base + lane]) : 0;
    for (int i = 0; i < m; ++i){
      int s = __shfl(sv, i);
      const uchar* hs = hq + (size_t)s*192;
      float b0 = (float)hs[lane];
      float b1 = (float)hs[64+lane];
      float b2 = (float)hs[128+lane];
      int g2 = s >> 4;
      float d0 = scaleV[g2], d1 = scaleV[NT+g2], d2 = scaleV[2*NT+g2];
      a0 = fmaf(d0, b0, a0); ss0 += d0;
      a1 = fmaf(d1, b1, a1); ss1 += d1;
      a2 = fmaf(d2, b2, a2); ss2 += d2;
    }
  }
  a0 -= 128.0f*ss0;
  a1 -= 128.0f*ss1;
  a2 -= 128.0f*ss2;
  float dv = dinv[n];
  float e0 = fmaxf(a0*dv + bv[hp],      0.f);
  float e1 = fmaxf(a1*dv + bv[64+hp],   0.f);
  float e2 = fmaxf(a2*dv + bv[128+hp],  0.f);
  ushort16* ep = emb + (size_t)n*NVH;
  __builtin_nontemporal_store((ushort16)bf16rne(e0), &ep[hp]);
  __builtin_nontemporal_store((ushort16)bf16rne(e1), &ep[64+hp]);
  __builtin_nontemporal_store((ushort16)bf16rne(e2), &ep[128+hp]);
  float w = na_w[hp];
  float s0 = e0*w, s1 = e1*w, s2 = e2*w;
  #pragma unroll
  for (int ofs = 32; ofs >= 1; ofs >>= 1){
    s0 += __shfl_xor(s0, ofs);
    s1 += __shfl_xor(s1, ofs);
    s2 += __shfl_xor(s2, ofs);
  }
  if (lane == 0){
    float nb = na_b[0];
    scores[n] = s0 + nb; scores[N + n] = s1 + nb; scores[2*N + n] = s2 + nb;
  }
}

// ---- global max per view (75 blocks -> 75 atomics total) ----
__global__ void k_max(const float* __restrict__ scores, int N, unsigned* __restrict__ maxkey){
  __shared__ float sh[256];
  int v = blockIdx.y;
  const float* sp = scores + (size_t)v*N;
  int base = blockIdx.x*2048 + threadIdx.x;
  float m = -3.0e38f;
  #pragma unroll
  for (int k = 0; k < 8; ++k){
    int i = base + k*256;
    if (i < N) m = fmaxf(m, sp[i]);
  }
  sh[threadIdx.x] = m; __syncthreads();
  for (int ofs = 128; ofs >= 1; ofs >>= 1){
    if (threadIdx.x < ofs) sh[threadIdx.x] = fmaxf(sh[threadIdx.x], sh[threadIdx.x+ofs]);
    __syncthreads();
  }
  if (threadIdx.x == 0) atomicMax(&maxkey[v], fkey(sh[0]));
}

// ---- sum(exp) per view + weighted sum over nodes, hierarchical ----
__global__ __launch_bounds__(256) void k_wsum(const ushort16* __restrict__ emb, const float* __restrict__ scores,
                                              const unsigned* __restrict__ maxkey, float* __restrict__ wsum,
                                              float* __restrict__ sumexp, int N){
  __shared__ float shw[4][NVH];
  __shared__ float shse[4][4];
  int t = threadIdx.x;
  int lane = t & 63;
  int wv = t >> 6;
  int gw = (blockIdx.x*blockDim.x + t) >> 6;
  int nw = (gridDim.x*blockDim.x) >> 6;
  float m0 = unkey(maxkey[0]), m1 = unkey(maxkey[1]), m2 = unkey(maxkey[2]);
  float w0=0.f, w1=0.f, w2=0.f, se0=0.f, se1=0.f, se2=0.f;
  for (int n = gw; n < N; n += nw){
    const ushort16* ep = emb + (size_t)n*NVH;
    float x0 = expf(scores[n]       - m0);
    float x1 = expf(scores[N + n]   - m1);
    float x2 = expf(scores[2*N + n] - m2);
    w0 += bfus(ep[lane])*x0; w1 += bfus(ep[64+lane])*x1; w2 += bfus(ep[128+lane])*x2;
    se0 += x0; se1 += x1; se2 += x2;
  }
  shw[wv][lane]     = w0;
  shw[wv][64+lane]  = w1;
  shw[wv][128+lane] = w2;
  #pragma unroll
  for (int ofs = 32; ofs >= 1; ofs >>= 1){
    se0 += __shfl_xor(se0, ofs);
    se1 += __shfl_xor(se1, ofs);
    se2 += __shfl_xor(se2, ofs);
  }
  if (lane == 0){ shse[wv][0] = se0; shse[wv][1] = se1; shse[wv][2] = se2; }
  __syncthreads();
  if (t < NVH){
    float s = shw[0][t] + shw[1][t] + shw[2][t] + shw[3][t];
    atomicAdd(&wsum[t], s);
  } else if (t >= NVH && t < NVH+3){
    int v = t - NVH;
    float s = shse[0][v] + shse[1][v] + shse[2][v] + shse[3][v];
    atomicAdd(&sumexp[v], s);
  }
}

// ---- view attention (tiny) ----
__global__ __launch_bounds__(64) void k_view(const float* __restrict__ wsum, const float* __restrict__ sumexp,
                                             const float* __restrict__ va_w1, const float* __restrict__ va_b1,
                                             const float* __restrict__ va_w2, const float* __restrict__ va_b2,
                                             float* __restrict__ g, float* __restrict__ out_vw, int N){
  __shared__ float avg[NV][64];
  __shared__ float z1[NV][32];
  int t = threadIdx.x;
  if (t < 64){
    for (int v = 0; v < NV; ++v) avg[v][t] = wsum[v*64+t] / (sumexp[v] * (float)N);
  }
  __syncthreads();
  if (t < 32){
    for (int v = 0; v < NV; ++v){
      float a = va_b1[t];
      for (int h = 0; h < 64; ++h) a += avg[v][h]*va_w1[h*32 + t];
      z1[v][t] = tanhf(a);
    }
  }
  __syncthreads();
  if (t == 0){
    float vs[NV];
    for (int v = 0; v < NV; ++v){
      float a = va_b2[0];
      for (int j = 0; j < 32; ++j) a += z1[v][j]*va_w2[j];
      vs[v] = a;
    }
    float m = fmaxf(vs[0], fmaxf(vs[1], vs[2]));
    float e0 = expf(vs[0]-m), e1 = expf(vs[1]-m), e2 = expf(vs[2]-m);
    float inv = 1.f/(e0+e1+e2);
    float vw0 = e0*inv, vw1 = e1*inv, vw2 = e2*inv;
    out_vw[0] = vw0; out_vw[1] = vw1; out_vw[2] = vw2;
    g[0] = vw0/sumexp[0]; g[1] = vw1/sumexp[1]; g[2] = vw2/sumexp[2];
  }
}

// ---- fused output + classifier + log_softmax (wave per node) ----
__global__ __launch_bounds__(256) void k_fused(const ushort16* __restrict__ emb, const float* __restrict__ scores,
                                               const unsigned* __restrict__ maxkey, const float* __restrict__ g,
                                               const float* __restrict__ cls_w, const float* __restrict__ cls_b,
                                               float* __restrict__ out, int N){
  int wid = (blockIdx.x*blockDim.x + threadIdx.x) >> 6;
  int lane = threadIdx.x & 63;
  if (wid >= N) return;
  int n = wid;
  float m0 = unkey(maxkey[0]), m1 = unkey(maxkey[1]), m2 = unkey(maxkey[2]);
  float w0 = expf(scores[n]       - m0)*g[0];
  float w1 = expf(scores[N + n]   - m1)*g[1];
  float w2 = expf(scores[2*N + n] - m2)*g[2];
  const ushort16* ep = emb + (size_t)n*NVH;
  float fu = bfus(ep[lane])*w0 + bfus(ep[64+lane])*w1 + bfus(ep[128+lane])*w2;
  out[(size_t)2*N + (size_t)n*64 + lane] = fu;
  float c0 = fu*cls_w[lane*2 + 0];
  float c1 = fu*cls_w[lane*2 + 1];
  #pragma unroll
  for (int ofs = 32; ofs >= 1; ofs >>= 1){
    c0 += __shfl_xor(c0, ofs);
    c1 += __shfl_xor(c1, ofs);
  }
  if (lane == 0){
    float l0 = c0 + cls_b[0], l1 = c1 + cls_b[1];
    float m = fmaxf(l0, l1);
    float lse = m + logf(expf(l0-m) + expf(l1-m));
    out[(size_t)n*2]     = l0 - lse;
    out[(size_t)n*2 + 1] = l1 - lse;
  }
}

extern "C" void kernel_launch(void* const* d_in, const int* in_sizes, int n_in,
                              void* d_out, int out_size, void* d_ws, size_t ws_size,
                              hipStream_t stream){
  const float* x     = (const float*)d_in[0];
  const int*   ei    = (const int*)d_in[1];
  const float* Wv    = (const float*)d_in[2];
  const float* bv    = (const float*)d_in[3];
  const float* na_w  = (const float*)d_in[4];
  const float* na_b  = (const float*)d_in[5];
  const float* va_w1 = (const float*)d_in[6];
  const float* va_b1 = (const float*)d_in[7];
  const float* va_w2 = (const float*)d_in[8];
  const float* va_b2 = (const float*)d_in[9];
  const float* cls_w = (const float*)d_in[10];
  const float* cls_b = (const float*)d_in[11];
  int N = in_sizes[0] / (NV*DIMX);
  int E = in_sizes[1] / 2;
  float* out = (float*)d_out;
  int NT = (N + 15) / 16;

  char* wptr = (char*)d_ws;
  size_t off = 0;
  auto alloc = [&](size_t bytes){ void* p = wptr + off; off += (bytes + 255) & ~255ull; return p; };
  uint32*    hq       = (uint32*)alloc((size_t)N*48*4);       // combined int8 table, 192B/node
  float*     scaleV   = (float*)alloc((size_t)3*NT*4);
  ushort16*  emb      = (ushort16*)alloc((size_t)N*NVH*2);
  int*       csr      = (int*)alloc((size_t)E*4);
  uint32*    ebuf     = (uint32*)alloc((size_t)E*4);
  int*       histT    = (int*)alloc((size_t)NBUK*NBLK*4);
  int*       rowstart = (int*)alloc((size_t)(N+1)*4);
  float*     dinv     = (float*)alloc((size_t)N*4);
  float*     scores   = (float*)alloc((size_t)3*N*4);
  unsigned*  maxkey   = (unsigned*)alloc(3*4);
  float*     sumexp   = (float*)alloc(3*4);
  float*     wsum     = (float*)alloc(192*4);
  float*     g        = (float*)alloc(3*4);
  uint32*    Wb       = (uint32*)alloc(3072*16);

  int EPB = (E + NBLK - 1) / NBLK;
  int nbuck = (N + 511) >> BSH;
  k_zero   <<<1, 256, 0, stream>>>(wsum, sumexp, maxkey);
  k_hist   <<<NBLK, 256, 0, stream>>>(ei, E, EPB, histT);
  k_hscan  <<<1, 1024, 0, stream>>>(histT);
  k_scatter<<<NBLK, 256, 0, stream>>>(ei, E, EPB, histT, ebuf);
  k_csr    <<<nbuck, 512, 0, stream>>>(ebuf, histT, E, N, rowstart, dinv, csr);
  k_wpack  <<<12, 256, 0, stream>>>(Wv, Wb);
  int hwaves = NT*3;
  k_h      <<<(hwaves*64+255)/256, 256, 0, stream>>>(x, Wb, dinv, hq, scaleV, N, NT);
  k_aggv   <<<(N*64+255)/256, 256, 0, stream>>>((const uchar*)hq, scaleV, rowstart, csr, dinv, bv,
                                                na_w, na_b, emb, scores, N, NT);
  dim3 gm((N+2047)/2048, NV);
  k_max    <<<gm, 256, 0, stream>>>(scores, N, maxkey);
  k_wsum   <<<304, 256, 0, stream>>>(emb, scores, maxkey, wsum, sumexp, N);
  k_view   <<<1, 64, 0, stream>>>(wsum, sumexp, va_w1, va_b1, va_w2, va_b2, g,
                                  out + (size_t)2*N + (size_t)N*64, N);
  k_fused  <<<(N*64+255)/256, 256, 0, stream>>>(emb, scores, maxkey, g, cls_w, cls_b, out, N);
}

// Round 9
// 164.545 us; speedup vs baseline: 3.4914x; 1.1210x over previous
//
#include <hip/hip_runtime.h>
#include <math.h>

#define NV 3
#define DIMX 128
#define HD 64
#define NVH 192
#define NBLK 256     // edge-partition blocks for hist/scatter
#define NBUK 128     // dst buckets of 512 nodes
#define BSH 9        // log2(512)

typedef unsigned int uint32;
typedef unsigned short ushort16;
typedef unsigned char uchar;
typedef __attribute__((ext_vector_type(8))) short short8;
typedef __attribute__((ext_vector_type(4))) float f32x4;

__device__ __forceinline__ unsigned fkey(float f){
  unsigned b = __float_as_uint(f);
  return (b & 0x80000000u) ? ~b : (b | 0x80000000u);
}
__device__ __forceinline__ float unkey(unsigned k){
  return __uint_as_float((k & 0x80000000u) ? (k ^ 0x80000000u) : ~k);
}
__device__ __forceinline__ uint32 bf16rne(float f){
  uint32 u = __float_as_uint(f);
  return (u + 0x7fffu + ((u >> 16) & 1u)) >> 16;
}
__device__ __forceinline__ float bfus(uint32 q){ return __uint_as_float(q << 16); }
__device__ __forceinline__ float ub0(uint32 p){ return (float)(p & 0xffu); }
__device__ __forceinline__ float ub1(uint32 p){ return (float)((p >> 8) & 0xffu); }
__device__ __forceinline__ float ub2(uint32 p){ return (float)((p >> 16) & 0xffu); }

// ---- zero the tiny accumulators ----
__global__ void k_zero(float* __restrict__ wsum, float* __restrict__ sumexp, unsigned* __restrict__ maxkey){
  int t = threadIdx.x;
  if (t < NVH) wsum[t] = 0.f;
  else if (t < NVH+3) sumexp[t-NVH] = 0.f;
  else if (t < NVH+6) maxkey[t-NVH-3] = 0u;
}

// ---- CSR build: two-level counting sort, LDS atomics only ----
__global__ __launch_bounds__(256) void k_hist(const int* __restrict__ ei, int E, int EPB,
                                              int* __restrict__ histT){
  __shared__ int sh[NBUK];
  int t = threadIdx.x, b = blockIdx.x;
  if (t < NBUK) sh[t] = 0;
  __syncthreads();
  int e0 = b*EPB, e1 = min(e0 + EPB, E);
  for (int i = e0 + t; i < e1; i += 256){
    int d = ei[E + i];
    atomicAdd(&sh[d >> BSH], 1);
  }
  __syncthreads();
  if (t < NBUK) histT[t*NBLK + b] = sh[t];
}

__global__ __launch_bounds__(1024) void k_hscan(int* __restrict__ histT){
  __shared__ int sh[1024];
  int t = threadIdx.x;
  int lo = t*32;
  int vals[32]; int s = 0;
  #pragma unroll
  for (int k = 0; k < 32; ++k){ vals[k] = histT[lo+k]; s += vals[k]; }
  sh[t] = s; __syncthreads();
  for (int ofs = 1; ofs < 1024; ofs <<= 1){
    int v = (t >= ofs) ? sh[t-ofs] : 0;
    __syncthreads();
    sh[t] += v;
    __syncthreads();
  }
  int run = sh[t] - s;
  #pragma unroll
  for (int k = 0; k < 32; ++k){ histT[lo+k] = run; run += vals[k]; }
}

// pack edge as (dst_local<<16)|src  (valid: src < 65536, dst_local < 512)
__global__ __launch_bounds__(256) void k_scatter(const int* __restrict__ ei, int E, int EPB,
                                                 const int* __restrict__ ofsT, uint32* __restrict__ ebuf){
  __shared__ int cur[NBUK];
  int t = threadIdx.x, b = blockIdx.x;
  if (t < NBUK) cur[t] = ofsT[t*NBLK + b];
  __syncthreads();
  int e0 = b*EPB, e1 = min(e0 + EPB, E);
  for (int i = e0 + t; i < e1; i += 256){
    int s = ei[i], d = ei[E + i];
    int pos = atomicAdd(&cur[d >> BSH], 1);
    ebuf[pos] = ((uint32)(d & 511) << 16) | (uint32)s;
  }
}

__global__ __launch_bounds__(512) void k_csr(const uint32* __restrict__ ebuf, const int* __restrict__ ofsT,
                                             int E, int N, int* __restrict__ rowstart,
                                             float* __restrict__ dinv, int* __restrict__ csr){
  __shared__ int cnt[512];
  __shared__ int pre[512];
  int t = threadIdx.x, b = blockIdx.x;
  int estart = ofsT[b*NBLK];
  int eend   = ((b+1)*NBLK < NBUK*NBLK) ? ofsT[(b+1)*NBLK] : E;
  int n0 = b << BSH;
  int nn = min(512, N - n0);
  cnt[t] = 0;
  __syncthreads();
  for (int i = estart + t; i < eend; i += 512){
    atomicAdd(&cnt[ebuf[i] >> 16], 1);
  }
  __syncthreads();
  int c = cnt[t];
  pre[t] = c;
  __syncthreads();
  for (int ofs = 1; ofs < 512; ofs <<= 1){
    int v = (t >= ofs) ? pre[t-ofs] : 0;
    __syncthreads();
    pre[t] += v;
    __syncthreads();
  }
  int excl = pre[t] - c;
  if (t < nn){
    rowstart[n0 + t] = estart + excl;
    dinv[n0 + t] = rsqrtf((float)(c + 1));
  }
  if (b == gridDim.x - 1 && t == 0) rowstart[N] = E;
  cnt[t] = estart + excl;
  __syncthreads();
  for (int i = estart + t; i < eend; i += 512){
    uint32 e = ebuf[i];
    int pos = atomicAdd(&cnt[e >> 16], 1);
    csr[pos] = (int)(e & 0xFFFFu);
  }
}

// ---- pack Wv into per-lane MFMA B-fragment order ----
__global__ __launch_bounds__(256) void k_wpack(const float* __restrict__ Wv, uint32* __restrict__ Wb){
  int t = blockIdx.x*blockDim.x + threadIdx.x;
  if (t >= 3072) return;
  int l = t & 63, s = (t >> 6) & 3, c = (t >> 8) & 3, v = t >> 10;
  int h = c*16 + (l & 15);
  int kbase = s*32 + (l >> 4)*8;
  const float* wp = Wv + v*8192 + h;
  uint32 o[4];
  #pragma unroll
  for (int jj = 0; jj < 4; ++jj){
    uint32 lo = bf16rne(wp[(kbase + 2*jj    )*64]);
    uint32 hi = bf16rne(wp[(kbase + 2*jj + 1)*64]);
    o[jj] = lo | (hi << 16);
  }
  Wb[t*4+0] = o[0]; Wb[t*4+1] = o[1]; Wb[t*4+2] = o[2]; Wb[t*4+3] = o[3];
}

// ---- MFMA linear transform, one wave per (16-node tile, view), fused int8 quant ----
// packed table: hq8[n*256 + h*4 + v] = int8(q+128) of view v, h-dim h
// per-(tile,view) scale in scale4[tile*4 + v] (float4-strided for one-load dequant)
__global__ __launch_bounds__(256) void k_h(const float* __restrict__ x, const uint32* __restrict__ Wb,
                                           const float* __restrict__ dinv,
                                           uchar* __restrict__ hq8, float* __restrict__ scale4,
                                           int N, int NT){
  int wv = (blockIdx.x*blockDim.x + threadIdx.x) >> 6;
  int lane = threadIdx.x & 63;
  int tile = wv / 3;
  int v = wv - tile*3;
  if (tile >= NT) return;
  int jrow = lane & 15;
  int kq   = lane >> 4;
  int nrow = tile*16 + jrow;
  const float* xr = x + (size_t)nrow*384 + v*128 + kq*8;
  const short8* WB = (const short8*)Wb;

  f32x4 acc[4] = {};
  #pragma unroll
  for (int s = 0; s < 4; ++s){
    const float* p = xr + s*32;
    float4 f = *(const float4*)p, g = *(const float4*)(p+4);
    short8 a;
    a[0]=(short)bf16rne(f.x); a[1]=(short)bf16rne(f.y); a[2]=(short)bf16rne(f.z); a[3]=(short)bf16rne(f.w);
    a[4]=(short)bf16rne(g.x); a[5]=(short)bf16rne(g.y); a[6]=(short)bf16rne(g.z); a[7]=(short)bf16rne(g.w);
    #pragma unroll
    for (int c = 0; c < 4; ++c){
      short8 b = WB[(v*4 + c)*256 + s*64 + lane];
      acc[c] = __builtin_amdgcn_mfma_f32_16x16x32_bf16(a, b, acc[c], 0, 0, 0);
    }
  }

  float vv[4][4];
  float mx = 0.f;
  #pragma unroll
  for (int r = 0; r < 4; ++r){
    int n = tile*16 + kq*4 + r;
    float dv = dinv[n];
    #pragma unroll
    for (int c = 0; c < 4; ++c){
      float t = acc[c][r]*dv;
      vv[c][r] = t;
      mx = fmaxf(mx, fabsf(t));
    }
  }
  #pragma unroll
  for (int ofs = 1; ofs < 64; ofs <<= 1) mx = fmaxf(mx, __shfl_xor(mx, ofs));
  float inv = (mx > 0.f) ? 127.0f/mx : 0.f;
  #pragma unroll
  for (int r = 0; r < 4; ++r){
    int n = tile*16 + kq*4 + r;
    #pragma unroll
    for (int c = 0; c < 4; ++c){
      uint32 q = (uint32)(int)(vv[c][r]*inv + 128.5f);
      hq8[(size_t)n*256 + (c*16 + jrow)*4 + v] = (uchar)q;
    }
  }
  if (lane == 0) scale4[tile*4 + v] = mx * (1.0f/127.0f);
}

// ---- fused 3-view aggregation: 1 dword gather + 1 float4 scale load per edge ----
__global__ __launch_bounds__(256) void k_aggv(const uint32* __restrict__ hq4, const float4* __restrict__ sc4,
                                              const int* __restrict__ rowstart, const int* __restrict__ csr,
                                              const float* __restrict__ dinv, const float* __restrict__ bv,
                                              const float* __restrict__ na_w, const float* __restrict__ na_b,
                                              ushort16* __restrict__ emb, float* __restrict__ scores, int N){
  int wid = (blockIdx.x*blockDim.x + threadIdx.x) >> 6;
  int lane = threadIdx.x & 63;
  if (wid >= N) return;
  int n = wid;
  // self-loop
  uint32 ps = hq4[(size_t)n*64 + lane];
  float4 cs = sc4[n >> 4];
  float a0 = cs.x*ub0(ps), a1 = cs.y*ub1(ps), a2 = cs.z*ub2(ps);
  float ss0 = cs.x, ss1 = cs.y, ss2 = cs.z;
  int r0 = rowstart[n], r1 = rowstart[n+1];
  for (int base = r0; base < r1; base += 64){
    int m = r1 - base; if (m > 64) m = 64;
    int sv = (lane < m) ? __builtin_nontemporal_load(&csr[base + lane]) : 0;
    int i = 0;
    for (; i + 3 < m; i += 4){
      int s0 = __shfl(sv, i), s1 = __shfl(sv, i+1), s2 = __shfl(sv, i+2), s3 = __shfl(sv, i+3);
      uint32 p0 = hq4[(size_t)s0*64 + lane];
      uint32 p1 = hq4[(size_t)s1*64 + lane];
      uint32 p2 = hq4[(size_t)s2*64 + lane];
      uint32 p3 = hq4[(size_t)s3*64 + lane];
      float4 f0 = sc4[s0 >> 4];
      float4 f1 = sc4[s1 >> 4];
      float4 f2 = sc4[s2 >> 4];
      float4 f3 = sc4[s3 >> 4];
      a0 = fmaf(f0.x, ub0(p0), a0); a1 = fmaf(f0.y, ub1(p0), a1); a2 = fmaf(f0.z, ub2(p0), a2);
      a0 = fmaf(f1.x, ub0(p1), a0); a1 = fmaf(f1.y, ub1(p1), a1); a2 = fmaf(f1.z, ub2(p1), a2);
      a0 = fmaf(f2.x, ub0(p2), a0); a1 = fmaf(f2.y, ub1(p2), a1); a2 = fmaf(f2.z, ub2(p2), a2);
      a0 = fmaf(f3.x, ub0(p3), a0); a1 = fmaf(f3.y, ub1(p3), a1); a2 = fmaf(f3.z, ub2(p3), a2);
      ss0 += f0.x + f1.x + f2.x + f3.x;
      ss1 += f0.y + f1.y + f2.y + f3.y;
      ss2 += f0.z + f1.z + f2.z + f3.z;
    }
    for (; i < m; ++i){
      int s = __shfl(sv, i);
      uint32 p = hq4[(size_t)s*64 + lane];
      float4 f = sc4[s >> 4];
      a0 = fmaf(f.x, ub0(p), a0); a1 = fmaf(f.y, ub1(p), a1); a2 = fmaf(f.z, ub2(p), a2);
      ss0 += f.x; ss1 += f.y; ss2 += f.z;
    }
  }
  a0 -= 128.0f*ss0;
  a1 -= 128.0f*ss1;
  a2 -= 128.0f*ss2;
  float dv = dinv[n];
  float e0 = fmaxf(a0*dv + bv[lane],      0.f);
  float e1 = fmaxf(a1*dv + bv[64+lane],   0.f);
  float e2 = fmaxf(a2*dv + bv[128+lane],  0.f);
  ushort16* ep = emb + (size_t)n*NVH;
  __builtin_nontemporal_store((ushort16)bf16rne(e0), &ep[lane]);
  __builtin_nontemporal_store((ushort16)bf16rne(e1), &ep[64+lane]);
  __builtin_nontemporal_store((ushort16)bf16rne(e2), &ep[128+lane]);
  float w = na_w[lane];
  float s0 = e0*w, s1 = e1*w, s2 = e2*w;
  #pragma unroll
  for (int ofs = 32; ofs >= 1; ofs >>= 1){
    s0 += __shfl_xor(s0, ofs);
    s1 += __shfl_xor(s1, ofs);
    s2 += __shfl_xor(s2, ofs);
  }
  if (lane == 0){
    float nb = na_b[0];
    scores[n] = s0 + nb; scores[N + n] = s1 + nb; scores[2*N + n] = s2 + nb;
  }
}

// ---- global max per view ----
__global__ void k_max(const float* __restrict__ scores, int N, unsigned* __restrict__ maxkey){
  __shared__ float sh[256];
  int v = blockIdx.y;
  const float* sp = scores + (size_t)v*N;
  int base = blockIdx.x*2048 + threadIdx.x;
  float m = -3.0e38f;
  #pragma unroll
  for (int k = 0; k < 8; ++k){
    int i = base + k*256;
    if (i < N) m = fmaxf(m, sp[i]);
  }
  sh[threadIdx.x] = m; __syncthreads();
  for (int ofs = 128; ofs >= 1; ofs >>= 1){
    if (threadIdx.x < ofs) sh[threadIdx.x] = fmaxf(sh[threadIdx.x], sh[threadIdx.x+ofs]);
    __syncthreads();
  }
  if (threadIdx.x == 0) atomicMax(&maxkey[v], fkey(sh[0]));
}

// ---- sum(exp) per view + weighted sum over nodes, hierarchical ----
__global__ __launch_bounds__(256) void k_wsum(const ushort16* __restrict__ emb, const float* __restrict__ scores,
                                              const unsigned* __restrict__ maxkey, float* __restrict__ wsum,
                                              float* __restrict__ sumexp, int N){
  __shared__ float shw[4][NVH];
  __shared__ float shse[4][4];
  int t = threadIdx.x;
  int lane = t & 63;
  int wv = t >> 6;
  int gw = (blockIdx.x*blockDim.x + t) >> 6;
  int nw = (gridDim.x*blockDim.x) >> 6;
  float m0 = unkey(maxkey[0]), m1 = unkey(maxkey[1]), m2 = unkey(maxkey[2]);
  float w0=0.f, w1=0.f, w2=0.f, se0=0.f, se1=0.f, se2=0.f;
  for (int n = gw; n < N; n += nw){
    const ushort16* ep = emb + (size_t)n*NVH;
    float x0 = expf(scores[n]       - m0);
    float x1 = expf(scores[N + n]   - m1);
    float x2 = expf(scores[2*N + n] - m2);
    w0 += bfus(ep[lane])*x0; w1 += bfus(ep[64+lane])*x1; w2 += bfus(ep[128+lane])*x2;
    se0 += x0; se1 += x1; se2 += x2;
  }
  shw[wv][lane]     = w0;
  shw[wv][64+lane]  = w1;
  shw[wv][128+lane] = w2;
  #pragma unroll
  for (int ofs = 32; ofs >= 1; ofs >>= 1){
    se0 += __shfl_xor(se0, ofs);
    se1 += __shfl_xor(se1, ofs);
    se2 += __shfl_xor(se2, ofs);
  }
  if (lane == 0){ shse[wv][0] = se0; shse[wv][1] = se1; shse[wv][2] = se2; }
  __syncthreads();
  if (t < NVH){
    float s = shw[0][t] + shw[1][t] + shw[2][t] + shw[3][t];
    atomicAdd(&wsum[t], s);
  } else if (t >= NVH && t < NVH+3){
    int v = t - NVH;
    float s = shse[0][v] + shse[1][v] + shse[2][v] + shse[3][v];
    atomicAdd(&sumexp[v], s);
  }
}

// ---- view attention (tiny) ----
__global__ __launch_bounds__(64) void k_view(const float* __restrict__ wsum, const float* __restrict__ sumexp,
                                             const float* __restrict__ va_w1, const float* __restrict__ va_b1,
                                             const float* __restrict__ va_w2, const float* __restrict__ va_b2,
                                             float* __restrict__ g, float* __restrict__ out_vw, int N){
  __shared__ float avg[NV][64];
  __shared__ float z1[NV][32];
  int t = threadIdx.x;
  if (t < 64){
    for (int v = 0; v < NV; ++v) avg[v][t] = wsum[v*64+t] / (sumexp[v] * (float)N);
  }
  __syncthreads();
  if (t < 32){
    for (int v = 0; v < NV; ++v){
      float a = va_b1[t];
      for (int h = 0; h < 64; ++h) a += avg[v][h]*va_w1[h*32 + t];
      z1[v][t] = tanhf(a);
    }
  }
  __syncthreads();
  if (t == 0){
    float vs[NV];
    for (int v = 0; v < NV; ++v){
      float a = va_b2[0];
      for (int j = 0; j < 32; ++j) a += z1[v][j]*va_w2[j];
      vs[v] = a;
    }
    float m = fmaxf(vs[0], fmaxf(vs[1], vs[2]));
    float e0 = expf(vs[0]-m), e1 = expf(vs[1]-m), e2 = expf(vs[2]-m);
    float inv = 1.f/(e0+e1+e2);
    float vw0 = e0*inv, vw1 = e1*inv, vw2 = e2*inv;
    out_vw[0] = vw0; out_vw[1] = vw1; out_vw[2] = vw2;
    g[0] = vw0/sumexp[0]; g[1] = vw1/sumexp[1]; g[2] = vw2/sumexp[2];
  }
}

// ---- fused output + classifier + log_softmax (wave per node) ----
__global__ __launch_bounds__(256) void k_fused(const ushort16* __restrict__ emb, const float* __restrict__ scores,
                                               const unsigned* __restrict__ maxkey, const float* __restrict__ g,
                                               const float* __restrict__ cls_w, const float* __restrict__ cls_b,
                                               float* __restrict__ out, int N){
  int wid = (blockIdx.x*blockDim.x + threadIdx.x) >> 6;
  int lane = threadIdx.x & 63;
  if (wid >= N) return;
  int n = wid;
  float m0 = unkey(maxkey[0]), m1 = unkey(maxkey[1]), m2 = unkey(maxkey[2]);
  float w0 = expf(scores[n]       - m0)*g[0];
  float w1 = expf(scores[N + n]   - m1)*g[1];
  float w2 = expf(scores[2*N + n] - m2)*g[2];
  const ushort16* ep = emb + (size_t)n*NVH;
  float fu = bfus(ep[lane])*w0 + bfus(ep[64+lane])*w1 + bfus(ep[128+lane])*w2;
  out[(size_t)2*N + (size_t)n*64 + lane] = fu;
  float c0 = fu*cls_w[lane*2 + 0];
  float c1 = fu*cls_w[lane*2 + 1];
  #pragma unroll
  for (int ofs = 32; ofs >= 1; ofs >>= 1){
    c0 += __shfl_xor(c0, ofs);
    c1 += __shfl_xor(c1, ofs);
  }
  if (lane == 0){
    float l0 = c0 + cls_b[0], l1 = c1 + cls_b[1];
    float m = fmaxf(l0, l1);
    float lse = m + logf(expf(l0-m) + expf(l1-m));
    out[(size_t)n*2]     = l0 - lse;
    out[(size_t)n*2 + 1] = l1 - lse;
  }
}

extern "C" void kernel_launch(void* const* d_in, const int* in_sizes, int n_in,
                              void* d_out, int out_size, void* d_ws, size_t ws_size,
                              hipStream_t stream){
  const float* x     = (const float*)d_in[0];
  const int*   ei    = (const int*)d_in[1];
  const float* Wv    = (const float*)d_in[2];
  const float* bv    = (const float*)d_in[3];
  const float* na_w  = (const float*)d_in[4];
  const float* na_b  = (const float*)d_in[5];
  const float* va_w1 = (const float*)d_in[6];
  const float* va_b1 = (const float*)d_in[7];
  const float* va_w2 = (const float*)d_in[8];
  const float* va_b2 = (const float*)d_in[9];
  const float* cls_w = (const float*)d_in[10];
  const float* cls_b = (const float*)d_in[11];
  int N = in_sizes[0] / (NV*DIMX);
  int E = in_sizes[1] / 2;
  float* out = (float*)d_out;
  int NT = (N + 15) / 16;

  char* wptr = (char*)d_ws;
  size_t off = 0;
  auto alloc = [&](size_t bytes){ void* p = wptr + off; off += (bytes + 255) & ~255ull; return p; };
  uchar*     hq       = (uchar*)alloc((size_t)N*256);         // packed int8 table, 256B/node
  float*     scale4   = (float*)alloc((size_t)NT*4*4);
  ushort16*  emb      = (ushort16*)alloc((size_t)N*NVH*2);
  int*       csr      = (int*)alloc((size_t)E*4);
  uint32*    ebuf     = (uint32*)alloc((size_t)E*4);
  int*       histT    = (int*)alloc((size_t)NBUK*NBLK*4);
  int*       rowstart = (int*)alloc((size_t)(N+1)*4);
  float*     dinv     = (float*)alloc((size_t)N*4);
  float*     scores   = (float*)alloc((size_t)3*N*4);
  unsigned*  maxkey   = (unsigned*)alloc(3*4);
  float*     sumexp   = (float*)alloc(3*4);
  float*     wsum     = (float*)alloc(192*4);
  float*     g        = (float*)alloc(3*4);
  uint32*    Wb       = (uint32*)alloc(3072*16);

  int EPB = (E + NBLK - 1) / NBLK;
  int nbuck = (N + 511) >> BSH;
  k_zero   <<<1, 256, 0, stream>>>(wsum, sumexp, maxkey);
  k_hist   <<<NBLK, 256, 0, stream>>>(ei, E, EPB, histT);
  k_hscan  <<<1, 1024, 0, stream>>>(histT);
  k_scatter<<<NBLK, 256, 0, stream>>>(ei, E, EPB, histT, ebuf);
  k_csr    <<<nbuck, 512, 0, stream>>>(ebuf, histT, E, N, rowstart, dinv, csr);
  k_wpack  <<<12, 256, 0, stream>>>(Wv, Wb);
  int hwaves = NT*3;
  k_h      <<<(hwaves*64+255)/256, 256, 0, stream>>>(x, Wb, dinv, hq, scale4, N, NT);
  k_aggv   <<<(N*64+255)/256, 256, 0, stream>>>((const uint32*)hq, (const float4*)scale4, rowstart, csr,
                                                dinv, bv, na_w, na_b, emb, scores, N);
  dim3 gm((N+2047)/2048, NV);
  k_max    <<<gm, 256, 0, stream>>>(scores, N, maxkey);
  k_wsum   <<<304, 256, 0, stream>>>(emb, scores, maxkey, wsum, sumexp, N);
  k_view   <<<1, 64, 0, stream>>>(wsum, sumexp, va_w1, va_b1, va_w2, va_b2, g,
                                  out + (size_t)2*N + (size_t)N*64, N);
  k_fused  <<<(N*64+255)/256, 256, 0, stream>>>(emb, scores, maxkey, g, cls_w, cls_b, out, N);
}